// Round 24
// baseline (59.369 us; speedup 1.0000x reference)
//
#include <hip/hip_runtime.h>
#include <hip/hip_fp16.h>

typedef _Float16 half8 __attribute__((ext_vector_type(8)));
typedef _Float16 half4v __attribute__((ext_vector_type(4)));
typedef float float4v __attribute__((ext_vector_type(4)));

#define E_DIM 300
#define KP 320               // padded K (10 MFMA k-steps of 32)
#define B_ 32
#define NROW_CDD 3200        // 32*5*20

// ---------------- Kernel 1: gather + l2-normalize CDD (A) rows only ---------------------
// grid 800, 256 threads = 4 rows/block. ~6 MB traffic.
__global__ __launch_bounds__(256) void gather_norm(const int* __restrict__ cand,
                                                   const float* __restrict__ emb,
                                                   _Float16* __restrict__ outH)
{
    int row  = blockIdx.x * 4 + (threadIdx.x >> 6);
    int lane = threadIdx.x & 63;
    int tok = cand[row];
    const float4* e4 = (const float4*)(emb + (size_t)tok * E_DIM);   // 75 float4/row

    float4 v0 = e4[lane];
    float4 v1 = {0.f, 0.f, 0.f, 0.f};
    if (lane < 11) v1 = e4[64 + lane];
    float ss = v0.x*v0.x + v0.y*v0.y + v0.z*v0.z + v0.w*v0.w
             + v1.x*v1.x + v1.y*v1.y + v1.z*v1.z + v1.w*v1.w;
#pragma unroll
    for (int off = 32; off; off >>= 1) ss += __shfl_xor(ss, off);
    float sc = 1.0f / fmaxf(sqrtf(ss), 1e-12f);

    _Float16* o = outH + (size_t)row * KP;
    half4v h0 = { (_Float16)(v0.x*sc), (_Float16)(v0.y*sc), (_Float16)(v0.z*sc), (_Float16)(v0.w*sc) };
    *(half4v*)(o + 4 * lane) = h0;
    if (lane < 11) {
        half4v h1 = { (_Float16)(v1.x*sc), (_Float16)(v1.y*sc), (_Float16)(v1.z*sc), (_Float16)(v1.w*sc) };
        *(half4v*)(o + 256 + 4 * lane) = h1;
    } else if (lane < 16) {
        half4v hz = { (_Float16)0.f, (_Float16)0.f, (_Float16)0.f, (_Float16)0.f };
        *(half4v*)(o + 256 + 4 * lane) = hz;      // zero k = 300..319
    }
}

// ---------------- Kernel 2: hybrid GEMM, A from ws (regs), B RAW from emb (LDS) ---------
// grid (16, 32) = 512 blocks (2/CU), 448 threads (7 waves). R17 structure, but B is
// staged raw from the (L3-resident) embedding: coalesced two-phase (11 float4/thread,
// tokens via LDS), fp32->fp16 convert on LDS write, per-row ss via LDS atomicAdd.
// Epilogue scales acc by invB[col]. Kills the 41 MB B-side ws round-trip.
__global__ __launch_bounds__(448, 2) void sim_gemm(const _Float16* __restrict__ wsA,
                                                   const int* __restrict__ clk,
                                                   const float* __restrict__ emb,
                                                   _Float16* __restrict__ simW)
{
    __shared__ __align__(16) char Bbuf[64 * 640 + 128];   // 41 KB (+swizzle guard)
    __shared__ _Float16 simT[100 * 66];                   // 13.2 KB
    __shared__ int tokS[64];
    __shared__ float ssAcc[64];

    int b = blockIdx.y, ntile = blockIdx.x;               // cols ntile*64..+63
    int tid = threadIdx.x;
    int wave = tid >> 6, lane = tid & 63;
    int g4 = lane >> 4, r16 = lane & 15;

    // ---- hoist A slice: 10 independent 16B loads (normalized fp16 ws) ----
    int rA = wave * 16 + r16; if (rA > 99) rA = 99;
    const char* pA = (const char*)(wsA + (size_t)(b * 100 + rA) * KP);
    half8 af[10];
#pragma unroll
    for (int k = 0; k < 10; ++k) af[k] = *(const half8*)(pA + k * 64 + g4 * 16);

    // ---- tokens + ss init ----
    if (tid < 64) {
        int col = ntile * 64 + tid; if (col > 999) col = 999;
        tokS[tid] = clk[b * 1000 + col];
        ssAcc[tid] = 0.f;
    }
    __syncthreads();

    // ---- stage B raw: 64 rows x 75 float4 = 4800 units, two-phase hoisted ----
    float4 bv[11];
#pragma unroll
    for (int j = 0; j < 11; ++j) {
        int u = tid + 448 * j; if (u > 4799) u = 4799;
        int r = u / 75, c = u - r * 75;
        bv[j] = *(const float4*)(emb + (size_t)tokS[r] * E_DIM + c * 4);
    }
#pragma unroll
    for (int j = 0; j < 11; ++j) {
        int u = tid + 448 * j;
        if (u < 4800) {
            int r = u / 75, c = u - r * 75;
            float4 v = bv[j];
            atomicAdd(&ssAcc[r], v.x*v.x + v.y*v.y + v.z*v.z + v.w*v.w);
            half4v h = { (_Float16)v.x, (_Float16)v.y, (_Float16)v.z, (_Float16)v.w };
            *(half4v*)(Bbuf + ((r * 640 + c * 8) ^ ((r & 7) << 4))) = h;
        }
    }
    // zero-pad k = 300..319 (bytes 600..639 of each row)
    if (tid < 320) {
        int r = tid / 5, j5 = tid - r * 5;
        half4v z = { (_Float16)0.f, (_Float16)0.f, (_Float16)0.f, (_Float16)0.f };
        *(half4v*)(Bbuf + ((r * 640 + 600 + j5 * 8) ^ ((r & 7) << 4))) = z;
    }
    __syncthreads();

    // ---- k-loop: 4 ds_read_b128 + 4 MFMA per k (unchanged R17 core) ----
    float4v acc[4];
#pragma unroll
    for (int n = 0; n < 4; ++n) acc[n] = (float4v){0.f, 0.f, 0.f, 0.f};

#pragma unroll
    for (int k = 0; k < 10; ++k) {
#pragma unroll
        for (int n = 0; n < 4; ++n) {
            int rB = n * 16 + r16;
            half8 bf = *(const half8*)(Bbuf + ((rB * 640 + k * 64 + g4 * 16) ^ ((rB & 7) << 4)));
            acc[n] = __builtin_amdgcn_mfma_f32_16x16x32_f16(af[k], bf, acc[n], 0, 0, 0);
        }
    }

    // ---- epilogue: per-lane invB for its 4 columns (ssAcc final since stage barrier) ----
    // C/D layout (validated r1-r23): col = lane&15 (B-row), row = (lane>>4)*4+j (A-row)
#pragma unroll
    for (int n = 0; n < 4; ++n) {
        float inv = 1.0f / fmaxf(sqrtf(ssAcc[n * 16 + r16]), 1e-12f);
#pragma unroll
        for (int j = 0; j < 4; ++j) {
            int r = wave * 16 + g4 * 4 + j;
            if (r < 100) simT[r * 66 + n * 16 + r16] = (_Float16)(acc[n][j] * inv);
        }
    }
    __syncthreads();

    // ---- coalesced fp16 write-out: 100 rows x 64 cols ----
    for (int u = tid; u < 6400; u += 448) {
        int r = u >> 6, c = u & 63;
        int gcol = ntile * 64 + c;
        if (gcol < 1000) simW[(size_t)(b * 100 + r) * 1000 + gcol] = simT[r * 66 + c];
    }
}

// ---------------- Kernel 3: gaussian kernels + log pooling, one block per sim row -------
__global__ __launch_bounds__(256) void knrm_pool(const _Float16* __restrict__ simW,
                                                 const float* __restrict__ cpad,
                                                 const float* __restrict__ hpad,
                                                 const float* __restrict__ ltr_w,
                                                 float* __restrict__ rowsum)
{
    __shared__ float sS[50 * 21];
    __shared__ float mS[50 * 21];
    __shared__ float wS[1000];
    __shared__ float part[4];

    int row = blockIdx.x;            // (b*5+c)*20 + s
    int b = row / 100;
    int tid = threadIdx.x;

    if (tid < 250) {
        int p = tid * 4;
        half4v hv = *(const half4v*)(simW + (size_t)row * 1000 + p);
        float4v mv = *(const float4v*)(hpad + (size_t)b * 1000 + p);
        *(float4v*)&wS[p] = *(const float4v*)(ltr_w + p);
#pragma unroll
        for (int q = 0; q < 4; ++q) {
            int pq = p + q, h = pq / 20, t = pq - h * 20;
            sS[h * 21 + t] = (float)hv[q];
            mS[h * 21 + t] = mv[q];
        }
    }
    __syncthreads();

    float val = 0.f;
    if (tid < 250) {
        int h = tid % 50, kq = tid / 50;     // kq 0..4, k = kq*4+j
        float bj[4], cj[4];
        bool is19[4];
#pragma unroll
        for (int j = 0; j < 4; ++j) {
            float mu = -0.9f + 0.1f * (float)(kq * 4 + j);
            bj[j] = 100.0f * mu;
            cj[j] = -50.0f * mu * mu;
            is19[j] = (kq * 4 + j) == 19;
        }
        float psum0 = 0.f, psum1 = 0.f, psum2 = 0.f, psum3 = 0.f;
        const float* sp = sS + h * 21;
        const float* mp = mS + h * 21;
#pragma unroll 4
        for (int t = 0; t < 20; ++t) {
            float s  = sp[t];
            float mm = mp[t];
            float d  = s - 1.0f;
            float arg19 = -500000.0f * d * d;
            float a0 = is19[0] ? arg19 : fmaf(fmaf(-50.0f, s, bj[0]), s, cj[0]);
            float a1 = is19[1] ? arg19 : fmaf(fmaf(-50.0f, s, bj[1]), s, cj[1]);
            float a2 = is19[2] ? arg19 : fmaf(fmaf(-50.0f, s, bj[2]), s, cj[2]);
            float a3 = is19[3] ? arg19 : fmaf(fmaf(-50.0f, s, bj[3]), s, cj[3]);
            psum0 = fmaf(__expf(a0), mm, psum0);
            psum1 = fmaf(__expf(a1), mm, psum1);
            psum2 = fmaf(__expf(a2), mm, psum2);
            psum3 = fmaf(__expf(a3), mm, psum3);
        }
        const float* wp = wS + h * 20 + kq * 4;
        val  = __logf(fmaxf(psum0, 1e-10f)) * wp[0];
        val += __logf(fmaxf(psum1, 1e-10f)) * wp[1];
        val += __logf(fmaxf(psum2, 1e-10f)) * wp[2];
        val += __logf(fmaxf(psum3, 1e-10f)) * wp[3];
    }
#pragma unroll
    for (int off = 32; off; off >>= 1) val += __shfl_down(val, off);
    int wave = tid >> 6, lane = tid & 63;
    if (lane == 0) part[wave] = val;
    __syncthreads();
    if (tid == 0)
        rowsum[row] = (part[0] + part[1] + part[2] + part[3]) * 0.01f * cpad[row];
}

// ---------------- Kernel 4: sum rows per (b,c) + bias + log_softmax over C=5 ------------
__global__ __launch_bounds__(64) void finalize(const float* __restrict__ rowsum,
                                               const float* __restrict__ ltr_b,
                                               float* __restrict__ out)
{
    int b = blockIdx.x;
    int tid = threadIdx.x;
    __shared__ float sc[5];
    if (tid < 5) {
        float a = ltr_b[0];
        const float* rp = rowsum + (b * 5 + tid) * 20;
#pragma unroll
        for (int s = 0; s < 20; ++s) a += rp[s];
        sc[tid] = a;
    }
    __syncthreads();
    if (tid < 5) {
        float m = fmaxf(fmaxf(fmaxf(sc[0], sc[1]), fmaxf(sc[2], sc[3])), sc[4]);
        float sum = 0.f;
#pragma unroll
        for (int i = 0; i < 5; ++i) sum += __expf(sc[i] - m);
        out[b * 5 + tid] = sc[tid] - m - __logf(sum);
    }
}

extern "C" void kernel_launch(void* const* d_in, const int* in_sizes, int n_in,
                              void* d_out, int out_size, void* d_ws, size_t ws_size,
                              hipStream_t stream)
{
    const int*   cand = (const int*)d_in[0];
    const int*   clk  = (const int*)d_in[1];
    const float* cpad = (const float*)d_in[2];
    const float* hpad = (const float*)d_in[3];
    const float* emb  = (const float*)d_in[4];
    const float* lw   = (const float*)d_in[5];
    const float* lb   = (const float*)d_in[6];
    float* out = (float*)d_out;

    _Float16* wsA  = (_Float16*)d_ws;                                      // 2.048 MB
    _Float16* simW = (_Float16*)((char*)d_ws + (size_t)NROW_CDD * KP * 2); // 6.4 MB
    float* rowsum  = (float*)((char*)simW + (size_t)B_ * 100 * 1000 * 2);  // 12.8 KB

    hipLaunchKernelGGL(gather_norm, dim3(NROW_CDD / 4), dim3(256), 0, stream,
                       cand, emb, wsA);
    hipLaunchKernelGGL(sim_gemm, dim3(16, B_), dim3(448), 0, stream,
                       wsA, clk, emb, simW);
    hipLaunchKernelGGL(knrm_pool, dim3(NROW_CDD), dim3(256), 0, stream,
                       simW, cpad, hpad, lw, rowsum);
    hipLaunchKernelGGL(finalize, dim3(B_), dim3(64), 0, stream, rowsum, lb, out);
}

// Round 25
// 44.233 us; speedup vs baseline: 1.3422x; 1.3422x over previous
//
#include <hip/hip_runtime.h>
#include <hip/hip_fp16.h>

typedef _Float16 half8 __attribute__((ext_vector_type(8)));
typedef _Float16 half4v __attribute__((ext_vector_type(4)));
typedef float float4v __attribute__((ext_vector_type(4)));

#define E_DIM 300
#define KP 320               // padded K (10 MFMA k-steps of 32)
#define B_ 32
#define NROW_CDD 3200        // 32*5*20
#define NROW_HIS 32000       // 32*50*20

typedef const void __attribute__((address_space(1))) gvoid;
typedef void __attribute__((address_space(3))) lvoid;
__device__ __forceinline__ void gload16(const void* g, void* l) {
    __builtin_amdgcn_global_load_lds((gvoid*)g, (lvoid*)l, 16, 0, 0);
}

// ---------------- Kernel 1: gather + l2-normalize (float4 loads, half4 stores) ----------
// grid 8800, 256 threads = 4 rows/block. [R23 verified]
__global__ __launch_bounds__(256) void gather_norm(const int* __restrict__ cand,
                                                   const int* __restrict__ clk,
                                                   const float* __restrict__ emb,
                                                   _Float16* __restrict__ outH)
{
    int row  = blockIdx.x * 4 + (threadIdx.x >> 6);
    int lane = threadIdx.x & 63;
    int tok = (row < NROW_CDD) ? cand[row] : clk[row - NROW_CDD];
    const float4* e4 = (const float4*)(emb + (size_t)tok * E_DIM);   // 75 float4/row

    float4 v0 = e4[lane];
    float4 v1 = {0.f, 0.f, 0.f, 0.f};
    if (lane < 11) v1 = e4[64 + lane];
    float ss = v0.x*v0.x + v0.y*v0.y + v0.z*v0.z + v0.w*v0.w
             + v1.x*v1.x + v1.y*v1.y + v1.z*v1.z + v1.w*v1.w;
#pragma unroll
    for (int off = 32; off; off >>= 1) ss += __shfl_xor(ss, off);
    float sc = 1.0f / fmaxf(sqrtf(ss), 1e-12f);

    _Float16* o = outH + (size_t)row * KP;
    half4v h0 = { (_Float16)(v0.x*sc), (_Float16)(v0.y*sc), (_Float16)(v0.z*sc), (_Float16)(v0.w*sc) };
    *(half4v*)(o + 4 * lane) = h0;
    if (lane < 11) {
        half4v h1 = { (_Float16)(v1.x*sc), (_Float16)(v1.y*sc), (_Float16)(v1.z*sc), (_Float16)(v1.w*sc) };
        *(half4v*)(o + 256 + 4 * lane) = h1;
    } else if (lane < 16) {
        half4v hz = { (_Float16)0.f, (_Float16)0.f, (_Float16)0.f, (_Float16)0.f };
        *(half4v*)(o + 256 + 4 * lane) = hz;      // zero k = 300..319
    }
}

// ---------------- Kernel 2: hybrid GEMM, B staged via async global_load_lds w=16 --------
// grid (16, 32) = 512 blocks, 448 threads (7 waves). A af[10] in regs (R17); B chunk
// staged by 40 DMA segments of 1024 B: linear LDS dest, pre-swizzled per-lane SOURCE
// (src = dest ^ ((row&7)<<4), in-row since 640 % 32 == 0); reads use the same XOR.
// LDS ~54 KB -> 2 blocks/CU.
__global__ __launch_bounds__(448, 2) void sim_gemm(const _Float16* __restrict__ wsH,
                                                   _Float16* __restrict__ simW)
{
    __shared__ __align__(1024) char Bbuf[64 * 640];       // 40960 B, 40 segments
    __shared__ _Float16 simT[100 * 66];                   // 13.2 KB

    int b = blockIdx.y, ntile = blockIdx.x;               // cols ntile*64..+63
    int tid = threadIdx.x;
    int wave = tid >> 6, lane = tid & 63;
    int g4 = lane >> 4, r16 = lane & 15;

    const char* gA = (const char*)(wsH + (size_t)b * 100 * KP);
    const char* gB = (const char*)(wsH + (size_t)(NROW_CDD + b * 1000 + ntile * 64) * KP);

    // ---- hoist A slice: 10 independent global 16B loads (this wave's 16 rows) ----
    int rA = wave * 16 + r16; if (rA > 99) rA = 99;
    const char* pA = gA + (size_t)rA * 640;
    half8 af[10];
#pragma unroll
    for (int k = 0; k < 10; ++k) af[k] = *(const half8*)(pA + k * 64 + g4 * 16);

    // ---- async stage B: 40 x 1024-B segments via global_load_lds (w=16) ----
    // dest byte (per lane) = s*1024 + lane*16 (HW: uniform base + lane*16);
    // src byte = dest ^ ((row&7)<<4). ntile 15 rows 40..63 overread in-allocation;
    // their columns (>=1000) are discarded at write-out.
#pragma unroll
    for (int c = 0; c < 6; ++c) {
        int s = wave * 6 + c;
        if (s < 40) {
            int dest = s * 1024 + lane * 16;
            int r = dest / 640;
            int src = dest ^ ((r & 7) << 4);
            gload16(gB + src, Bbuf + s * 1024);
        }
    }
    __syncthreads();   // drains vmcnt(0) incl. the DMA loads

    // ---- k-loop: 4 ds_read_b128 + 4 MFMA per k (R17 core, XOR-swizzled reads) ----
    float4v acc[4];
#pragma unroll
    for (int n = 0; n < 4; ++n) acc[n] = (float4v){0.f, 0.f, 0.f, 0.f};

#pragma unroll
    for (int k = 0; k < 10; ++k) {
#pragma unroll
        for (int n = 0; n < 4; ++n) {
            int rB = n * 16 + r16;
            half8 bf = *(const half8*)(Bbuf + ((rB * 640 + k * 64 + g4 * 16) ^ ((rB & 7) << 4)));
            acc[n] = __builtin_amdgcn_mfma_f32_16x16x32_f16(af[k], bf, acc[n], 0, 0, 0);
        }
    }

    // C/D layout (validated r1-r24): col = lane&15 (B-row), row = (lane>>4)*4+j (A-row)
#pragma unroll
    for (int n = 0; n < 4; ++n) {
#pragma unroll
        for (int j = 0; j < 4; ++j) {
            int r = wave * 16 + g4 * 4 + j;
            if (r < 100) simT[r * 66 + n * 16 + r16] = (_Float16)acc[n][j];
        }
    }
    __syncthreads();

    // ---- coalesced fp16 write-out: 100 rows x 64 cols ----
    for (int u = tid; u < 6400; u += 448) {
        int r = u >> 6, c = u & 63;
        int gcol = ntile * 64 + c;
        if (gcol < 1000) simW[(size_t)(b * 100 + r) * 1000 + gcol] = simT[r * 66 + c];
    }
}

// ---------------- Kernel 3: gaussian kernels + log pooling, one block per sim row -------
__global__ __launch_bounds__(256) void knrm_pool(const _Float16* __restrict__ simW,
                                                 const float* __restrict__ cpad,
                                                 const float* __restrict__ hpad,
                                                 const float* __restrict__ ltr_w,
                                                 float* __restrict__ rowsum)
{
    __shared__ float sS[50 * 21];
    __shared__ float mS[50 * 21];
    __shared__ float wS[1000];
    __shared__ float part[4];

    int row = blockIdx.x;            // (b*5+c)*20 + s
    int b = row / 100;
    int tid = threadIdx.x;

    if (tid < 250) {
        int p = tid * 4;
        half4v hv = *(const half4v*)(simW + (size_t)row * 1000 + p);
        float4v mv = *(const float4v*)(hpad + (size_t)b * 1000 + p);
        *(float4v*)&wS[p] = *(const float4v*)(ltr_w + p);
#pragma unroll
        for (int q = 0; q < 4; ++q) {
            int pq = p + q, h = pq / 20, t = pq - h * 20;
            sS[h * 21 + t] = (float)hv[q];
            mS[h * 21 + t] = mv[q];
        }
    }
    __syncthreads();

    float val = 0.f;
    if (tid < 250) {
        int h = tid % 50, kq = tid / 50;     // kq 0..4, k = kq*4+j
        float bj[4], cj[4];
        bool is19[4];
#pragma unroll
        for (int j = 0; j < 4; ++j) {
            float mu = -0.9f + 0.1f * (float)(kq * 4 + j);
            bj[j] = 100.0f * mu;
            cj[j] = -50.0f * mu * mu;
            is19[j] = (kq * 4 + j) == 19;
        }
        float psum0 = 0.f, psum1 = 0.f, psum2 = 0.f, psum3 = 0.f;
        const float* sp = sS + h * 21;
        const float* mp = mS + h * 21;
#pragma unroll 4
        for (int t = 0; t < 20; ++t) {
            float s  = sp[t];
            float mm = mp[t];
            float d  = s - 1.0f;
            float arg19 = -500000.0f * d * d;
            float a0 = is19[0] ? arg19 : fmaf(fmaf(-50.0f, s, bj[0]), s, cj[0]);
            float a1 = is19[1] ? arg19 : fmaf(fmaf(-50.0f, s, bj[1]), s, cj[1]);
            float a2 = is19[2] ? arg19 : fmaf(fmaf(-50.0f, s, bj[2]), s, cj[2]);
            float a3 = is19[3] ? arg19 : fmaf(fmaf(-50.0f, s, bj[3]), s, cj[3]);
            psum0 = fmaf(__expf(a0), mm, psum0);
            psum1 = fmaf(__expf(a1), mm, psum1);
            psum2 = fmaf(__expf(a2), mm, psum2);
            psum3 = fmaf(__expf(a3), mm, psum3);
        }
        const float* wp = wS + h * 20 + kq * 4;
        val  = __logf(fmaxf(psum0, 1e-10f)) * wp[0];
        val += __logf(fmaxf(psum1, 1e-10f)) * wp[1];
        val += __logf(fmaxf(psum2, 1e-10f)) * wp[2];
        val += __logf(fmaxf(psum3, 1e-10f)) * wp[3];
    }
#pragma unroll
    for (int off = 32; off; off >>= 1) val += __shfl_down(val, off);
    int wave = tid >> 6, lane = tid & 63;
    if (lane == 0) part[wave] = val;
    __syncthreads();
    if (tid == 0)
        rowsum[row] = (part[0] + part[1] + part[2] + part[3]) * 0.01f * cpad[row];
}

// ---------------- Kernel 4: sum rows per (b,c) + bias + log_softmax over C=5 ------------
__global__ __launch_bounds__(64) void finalize(const float* __restrict__ rowsum,
                                               const float* __restrict__ ltr_b,
                                               float* __restrict__ out)
{
    int b = blockIdx.x;
    int tid = threadIdx.x;
    __shared__ float sc[5];
    if (tid < 5) {
        float a = ltr_b[0];
        const float* rp = rowsum + (b * 5 + tid) * 20;
#pragma unroll
        for (int s = 0; s < 20; ++s) a += rp[s];
        sc[tid] = a;
    }
    __syncthreads();
    if (tid < 5) {
        float m = fmaxf(fmaxf(fmaxf(sc[0], sc[1]), fmaxf(sc[2], sc[3])), sc[4]);
        float sum = 0.f;
#pragma unroll
        for (int i = 0; i < 5; ++i) sum += __expf(sc[i] - m);
        out[b * 5 + tid] = sc[tid] - m - __logf(sum);
    }
}

extern "C" void kernel_launch(void* const* d_in, const int* in_sizes, int n_in,
                              void* d_out, int out_size, void* d_ws, size_t ws_size,
                              hipStream_t stream)
{
    const int*   cand = (const int*)d_in[0];
    const int*   clk  = (const int*)d_in[1];
    const float* cpad = (const float*)d_in[2];
    const float* hpad = (const float*)d_in[3];
    const float* emb  = (const float*)d_in[4];
    const float* lw   = (const float*)d_in[5];
    const float* lb   = (const float*)d_in[6];
    float* out = (float*)d_out;

    _Float16* wsH  = (_Float16*)d_ws;                                                   // 22.528 MB
    _Float16* simW = (_Float16*)((char*)d_ws + (size_t)(NROW_CDD + NROW_HIS) * KP * 2); // 6.4 MB
    float* rowsum  = (float*)((char*)simW + (size_t)B_ * 100 * 1000 * 2);               // 12.8 KB

    hipLaunchKernelGGL(gather_norm, dim3((NROW_CDD + NROW_HIS) / 4), dim3(256), 0, stream,
                       cand, clk, emb, wsH);
    hipLaunchKernelGGL(sim_gemm, dim3(16, B_), dim3(448), 0, stream, wsH, simW);
    hipLaunchKernelGGL(knrm_pool, dim3(NROW_CDD), dim3(256), 0, stream,
                       simW, cpad, hpad, lw, rowsum);
    hipLaunchKernelGGL(finalize, dim3(B_), dim3(64), 0, stream, rowsum, lb, out);
}

// Round 26
// 43.684 us; speedup vs baseline: 1.3590x; 1.0126x over previous
//
#include <hip/hip_runtime.h>
#include <hip/hip_fp16.h>

typedef _Float16 half8 __attribute__((ext_vector_type(8)));
typedef _Float16 half4v __attribute__((ext_vector_type(4)));
typedef float float4v __attribute__((ext_vector_type(4)));

#define E_DIM 300
#define KP 320               // padded K (10 MFMA k-steps of 32)
#define B_ 32
#define NROW_CDD 3200        // 32*5*20
#define NROW_HIS 32000       // 32*50*20

typedef const void __attribute__((address_space(1))) gvoid;
typedef void __attribute__((address_space(3))) lvoid;
__device__ __forceinline__ void gload16(const void* g, void* l) {
    __builtin_amdgcn_global_load_lds((gvoid*)g, (lvoid*)l, 16, 0, 0);
}

// ---------------- Kernel 1: gather + l2-normalize (float4 loads, half4 stores) ----------
// grid 8800, 256 threads = 4 rows/block. [R23/R25 verified]
__global__ __launch_bounds__(256) void gather_norm(const int* __restrict__ cand,
                                                   const int* __restrict__ clk,
                                                   const float* __restrict__ emb,
                                                   _Float16* __restrict__ outH)
{
    int row  = blockIdx.x * 4 + (threadIdx.x >> 6);
    int lane = threadIdx.x & 63;
    int tok = (row < NROW_CDD) ? cand[row] : clk[row - NROW_CDD];
    const float4* e4 = (const float4*)(emb + (size_t)tok * E_DIM);   // 75 float4/row

    float4 v0 = e4[lane];
    float4 v1 = {0.f, 0.f, 0.f, 0.f};
    if (lane < 11) v1 = e4[64 + lane];
    float ss = v0.x*v0.x + v0.y*v0.y + v0.z*v0.z + v0.w*v0.w
             + v1.x*v1.x + v1.y*v1.y + v1.z*v1.z + v1.w*v1.w;
#pragma unroll
    for (int off = 32; off; off >>= 1) ss += __shfl_xor(ss, off);
    float sc = 1.0f / fmaxf(sqrtf(ss), 1e-12f);

    _Float16* o = outH + (size_t)row * KP;
    half4v h0 = { (_Float16)(v0.x*sc), (_Float16)(v0.y*sc), (_Float16)(v0.z*sc), (_Float16)(v0.w*sc) };
    *(half4v*)(o + 4 * lane) = h0;
    if (lane < 11) {
        half4v h1 = { (_Float16)(v1.x*sc), (_Float16)(v1.y*sc), (_Float16)(v1.z*sc), (_Float16)(v1.w*sc) };
        *(half4v*)(o + 256 + 4 * lane) = h1;
    } else if (lane < 16) {
        half4v hz = { (_Float16)0.f, (_Float16)0.f, (_Float16)0.f, (_Float16)0.f };
        *(half4v*)(o + 256 + 4 * lane) = hz;      // zero k = 300..319
    }
}

// ---------------- Kernel 2: hybrid GEMM, async-DMA B staging, 3 blocks/CU ---------------
// grid (16, 32) = 512 blocks, 448 threads (7 waves). A af[10] in regs; B via 40x1024B
// global_load_lds segments (linear dest, pre-swizzled source). LDS 53760 B and
// __launch_bounds__(448,6) (VGPR cap 85) -> 3 blocks/CU: one block's stage burst
// overlaps two others' k-loops.
__global__ __launch_bounds__(448, 6) void sim_gemm(const _Float16* __restrict__ wsH,
                                                   _Float16* __restrict__ simW)
{
    __shared__ __align__(1024) char Bbuf[64 * 640];       // 40960 B, 40 DMA segments
    __shared__ _Float16 simT[100 * 64];                   // 12800 B, stride 64

    int b = blockIdx.y, ntile = blockIdx.x;               // cols ntile*64..+63
    int tid = threadIdx.x;
    int wave = tid >> 6, lane = tid & 63;
    int g4 = lane >> 4, r16 = lane & 15;

    const char* gA = (const char*)(wsH + (size_t)b * 100 * KP);
    const char* gB = (const char*)(wsH + (size_t)(NROW_CDD + b * 1000 + ntile * 64) * KP);

    // ---- hoist A slice: 10 independent global 16B loads (this wave's 16 rows) ----
    int rA = wave * 16 + r16; if (rA > 99) rA = 99;
    const char* pA = gA + (size_t)rA * 640;
    half8 af[10];
#pragma unroll
    for (int k = 0; k < 10; ++k) af[k] = *(const half8*)(pA + k * 64 + g4 * 16);

    // ---- async stage B: 40 x 1024-B segments via global_load_lds (w=16) ----
    // dest = s*1024 + lane*16 (HW: uniform base + lane*16); src = dest ^ ((row&7)<<4)
    // (in-row: 640 % 32 == 0). ntile 15 rows 40..63 overread in-allocation; cols >=1000
    // discarded at write-out.
#pragma unroll
    for (int c = 0; c < 6; ++c) {
        int s = wave * 6 + c;
        if (s < 40) {
            int dest = s * 1024 + lane * 16;
            int r = dest / 640;
            int src = dest ^ ((r & 7) << 4);
            gload16(gB + src, Bbuf + s * 1024);
        }
    }
    __syncthreads();   // drains vmcnt(0) incl. the DMA loads

    // ---- k-loop: 4 ds_read_b128 + 4 MFMA per k (XOR-swizzled reads) ----
    float4v acc[4];
#pragma unroll
    for (int n = 0; n < 4; ++n) acc[n] = (float4v){0.f, 0.f, 0.f, 0.f};

#pragma unroll
    for (int k = 0; k < 10; ++k) {
#pragma unroll
        for (int n = 0; n < 4; ++n) {
            int rB = n * 16 + r16;
            half8 bf = *(const half8*)(Bbuf + ((rB * 640 + k * 64 + g4 * 16) ^ ((rB & 7) << 4)));
            acc[n] = __builtin_amdgcn_mfma_f32_16x16x32_f16(af[k], bf, acc[n], 0, 0, 0);
        }
    }

    // C/D layout (validated r1-r25): col = lane&15 (B-row), row = (lane>>4)*4+j (A-row)
#pragma unroll
    for (int n = 0; n < 4; ++n) {
#pragma unroll
        for (int j = 0; j < 4; ++j) {
            int r = wave * 16 + g4 * 4 + j;
            if (r < 100) simT[r * 64 + n * 16 + r16] = (_Float16)acc[n][j];
        }
    }
    __syncthreads();

    // ---- coalesced fp16 write-out: 100 rows x 64 cols (half4 units) ----
    for (int u = tid; u < 1600; u += 448) {
        int r = u >> 4, c4 = u & 15;
        int gcol = ntile * 64 + c4 * 4;
        if (gcol < 1000)
            *(half4v*)(simW + (size_t)(b * 100 + r) * 1000 + gcol) =
                *(half4v*)(simT + r * 64 + c4 * 4);
    }
}

// ---------------- Kernel 3: gaussian kernels + log pooling, one block per sim row -------
__global__ __launch_bounds__(256) void knrm_pool(const _Float16* __restrict__ simW,
                                                 const float* __restrict__ cpad,
                                                 const float* __restrict__ hpad,
                                                 const float* __restrict__ ltr_w,
                                                 float* __restrict__ rowsum)
{
    __shared__ float sS[50 * 21];
    __shared__ float mS[50 * 21];
    __shared__ float wS[1000];
    __shared__ float part[4];

    int row = blockIdx.x;            // (b*5+c)*20 + s
    int b = row / 100;
    int tid = threadIdx.x;

    if (tid < 250) {
        int p = tid * 4;
        half4v hv = *(const half4v*)(simW + (size_t)row * 1000 + p);
        float4v mv = *(const float4v*)(hpad + (size_t)b * 1000 + p);
        *(float4v*)&wS[p] = *(const float4v*)(ltr_w + p);
#pragma unroll
        for (int q = 0; q < 4; ++q) {
            int pq = p + q, h = pq / 20, t = pq - h * 20;
            sS[h * 21 + t] = (float)hv[q];
            mS[h * 21 + t] = mv[q];
        }
    }
    __syncthreads();

    float val = 0.f;
    if (tid < 250) {
        int h = tid % 50, kq = tid / 50;     // kq 0..4, k = kq*4+j
        float bj[4], cj[4];
        bool is19[4];
#pragma unroll
        for (int j = 0; j < 4; ++j) {
            float mu = -0.9f + 0.1f * (float)(kq * 4 + j);
            bj[j] = 100.0f * mu;
            cj[j] = -50.0f * mu * mu;
            is19[j] = (kq * 4 + j) == 19;
        }
        float psum0 = 0.f, psum1 = 0.f, psum2 = 0.f, psum3 = 0.f;
        const float* sp = sS + h * 21;
        const float* mp = mS + h * 21;
#pragma unroll 4
        for (int t = 0; t < 20; ++t) {
            float s  = sp[t];
            float mm = mp[t];
            float d  = s - 1.0f;
            float arg19 = -500000.0f * d * d;
            float a0 = is19[0] ? arg19 : fmaf(fmaf(-50.0f, s, bj[0]), s, cj[0]);
            float a1 = is19[1] ? arg19 : fmaf(fmaf(-50.0f, s, bj[1]), s, cj[1]);
            float a2 = is19[2] ? arg19 : fmaf(fmaf(-50.0f, s, bj[2]), s, cj[2]);
            float a3 = is19[3] ? arg19 : fmaf(fmaf(-50.0f, s, bj[3]), s, cj[3]);
            psum0 = fmaf(__expf(a0), mm, psum0);
            psum1 = fmaf(__expf(a1), mm, psum1);
            psum2 = fmaf(__expf(a2), mm, psum2);
            psum3 = fmaf(__expf(a3), mm, psum3);
        }
        const float* wp = wS + h * 20 + kq * 4;
        val  = __logf(fmaxf(psum0, 1e-10f)) * wp[0];
        val += __logf(fmaxf(psum1, 1e-10f)) * wp[1];
        val += __logf(fmaxf(psum2, 1e-10f)) * wp[2];
        val += __logf(fmaxf(psum3, 1e-10f)) * wp[3];
    }
#pragma unroll
    for (int off = 32; off; off >>= 1) val += __shfl_down(val, off);
    int wave = tid >> 6, lane = tid & 63;
    if (lane == 0) part[wave] = val;
    __syncthreads();
    if (tid == 0)
        rowsum[row] = (part[0] + part[1] + part[2] + part[3]) * 0.01f * cpad[row];
}

// ---------------- Kernel 4: sum rows per (b,c) + bias + log_softmax over C=5 ------------
__global__ __launch_bounds__(64) void finalize(const float* __restrict__ rowsum,
                                               const float* __restrict__ ltr_b,
                                               float* __restrict__ out)
{
    int b = blockIdx.x;
    int tid = threadIdx.x;
    __shared__ float sc[5];
    if (tid < 5) {
        float a = ltr_b[0];
        const float* rp = rowsum + (b * 5 + tid) * 20;
#pragma unroll
        for (int s = 0; s < 20; ++s) a += rp[s];
        sc[tid] = a;
    }
    __syncthreads();
    if (tid < 5) {
        float m = fmaxf(fmaxf(fmaxf(sc[0], sc[1]), fmaxf(sc[2], sc[3])), sc[4]);
        float sum = 0.f;
#pragma unroll
        for (int i = 0; i < 5; ++i) sum += __expf(sc[i] - m);
        out[b * 5 + tid] = sc[tid] - m - __logf(sum);
    }
}

extern "C" void kernel_launch(void* const* d_in, const int* in_sizes, int n_in,
                              void* d_out, int out_size, void* d_ws, size_t ws_size,
                              hipStream_t stream)
{
    const int*   cand = (const int*)d_in[0];
    const int*   clk  = (const int*)d_in[1];
    const float* cpad = (const float*)d_in[2];
    const float* hpad = (const float*)d_in[3];
    const float* emb  = (const float*)d_in[4];
    const float* lw   = (const float*)d_in[5];
    const float* lb   = (const float*)d_in[6];
    float* out = (float*)d_out;

    _Float16* wsH  = (_Float16*)d_ws;                                                   // 22.528 MB
    _Float16* simW = (_Float16*)((char*)d_ws + (size_t)(NROW_CDD + NROW_HIS) * KP * 2); // 6.4 MB
    float* rowsum  = (float*)((char*)simW + (size_t)B_ * 100 * 1000 * 2);               // 12.8 KB

    hipLaunchKernelGGL(gather_norm, dim3((NROW_CDD + NROW_HIS) / 4), dim3(256), 0, stream,
                       cand, clk, emb, wsH);
    hipLaunchKernelGGL(sim_gemm, dim3(16, B_), dim3(448), 0, stream, wsH, simW);
    hipLaunchKernelGGL(knrm_pool, dim3(NROW_CDD), dim3(256), 0, stream,
                       simW, cpad, hpad, lw, rowsum);
    hipLaunchKernelGGL(finalize, dim3(B_), dim3(64), 0, stream, rowsum, lb, out);
}